// Round 1
// baseline (178.402 us; speedup 1.0000x reference)
//
#include <hip/hip_runtime.h>
#include <math.h>

#define NUM_AA   21
#define NUM_RBF  64
#define OUT_DIM  387          // 1 + 21 + 21 + 64 + 42 + 42 + 196
#define SCALE    0.1f
#define EPS_C    1e-8f
#define WAVES_PER_BLOCK 4

// One 64-lane wave per edge. Per-wave LDS scratch:
// [0..41]  a14s  (src atom14 * SCALE, a-major, i-minor)
// [42..83] a14d  (dst atom14 * SCALE)
// [84..92] rotS  (rot[src], row-major j*3+i)
// [93..95] tS    (trans[src] * SCALE)
// [96..137]  locS (src local coords)
// [138..179] locD (dst-in-src-frame local coords)
__global__ __launch_bounds__(256) void edge_feat_kernel(
    const float* __restrict__ A,    // (N,14,3) decoded_atom14
    const float* __restrict__ R,    // (N,3,3)  rot
    const float* __restrict__ T,    // (N,3)    trans
    const float* __restrict__ LG,   // (N,21)   decoded_seq_logits
    const int*   __restrict__ EI,   // (2,E)    edge_index  [0]=dst, [1]=src
    float* __restrict__ out,        // (E,387)
    int E)
{
    __shared__ float sh[WAVES_PER_BLOCK][180];
    __shared__ int   seqsh[WAVES_PER_BLOCK][2];

    const int wv   = threadIdx.x >> 6;
    const int lane = threadIdx.x & 63;
    const int e    = blockIdx.x * WAVES_PER_BLOCK + wv;
    const bool valid = (e < E);
    const int ec = valid ? e : 0;

    const int dst = EI[ec];
    const int src = EI[E + ec];

    float* a14s = sh[wv];
    float* a14d = sh[wv] + 42;
    float* rotS = sh[wv] + 84;
    float* tS   = sh[wv] + 93;
    float* locS = sh[wv] + 96;
    float* locD = sh[wv] + 138;

    if (lane < 42) {
        a14s[lane] = A[(size_t)src * 42 + lane] * SCALE;
        a14d[lane] = A[(size_t)dst * 42 + lane] * SCALE;
    } else if (lane < 51) {
        rotS[lane - 42] = R[(size_t)src * 9 + (lane - 42)];
    } else if (lane < 54) {
        tS[lane - 51] = T[(size_t)src * 3 + (lane - 51)] * SCALE;
    } else if (lane == 54 || lane == 55) {
        // argmax over 21 logits (first-max wins, matching np/jnp.argmax)
        const int node = (lane == 54) ? src : dst;
        const float* lg = LG + (size_t)node * NUM_AA;
        float best = lg[0]; int bi = 0;
        #pragma unroll
        for (int j = 1; j < NUM_AA; ++j) {
            float v = lg[j];
            if (v > best) { best = v; bi = j; }
        }
        seqsh[wv][lane - 54] = bi;
    }
    __syncthreads();

    if (lane < 42) {
        const int a = lane / 3;
        const int i = lane - a * 3;
        // local[a,i] = sum_j rot[j,i] * (x[a,j] - t[j])
        const float r0 = rotS[0 * 3 + i];
        const float r1 = rotS[1 * 3 + i];
        const float r2 = rotS[2 * 3 + i];
        const float t0 = tS[0], t1 = tS[1], t2 = tS[2];
        locS[lane] = r0 * (a14s[a * 3 + 0] - t0)
                   + r1 * (a14s[a * 3 + 1] - t1)
                   + r2 * (a14s[a * 3 + 2] - t2);
        locD[lane] = r0 * (a14d[a * 3 + 0] - t0)
                   + r1 * (a14d[a * 3 + 1] - t1)
                   + r2 * (a14d[a * 3 + 2] - t2);
    }
    __syncthreads();

    // CA (atom index 1) distance in the global (scaled) frame
    const float dx = a14d[3] - a14s[3];
    const float dy = a14d[4] - a14s[4];
    const float dz = a14d[5] - a14s[5];
    const float dca = sqrtf(dx * dx + dy * dy + dz * dz);
    const int seqS = seqsh[wv][0];
    const int seqD = seqsh[wv][1];

    if (!valid) return;   // no barriers after this point

    float* o = out + (size_t)e * OUT_DIM;
    #pragma unroll
    for (int it = 0; it < 7; ++it) {
        const int idx = lane + it * 64;
        if (idx >= OUT_DIM) break;
        float v;
        if (idx == 0) {
            v = 1.0f;
        } else if (idx < 22) {
            v = (idx - 1 == seqS) ? 1.0f : 0.0f;
        } else if (idx < 43) {
            v = (idx - 22 == seqD) ? 1.0f : 0.0f;
        } else if (idx < 107) {
            const float mu = (float)(idx - 43) * (20.0f / 63.0f);
            const float z = (dca - mu) * 3.2f;       // 1/sigma = NUM_RBF/20 = 3.2
            v = expf(-z * z);
        } else if (idx < 149) {
            v = locS[idx - 107];
        } else if (idx < 191) {
            v = locD[idx - 149];
        } else {
            const int p = idx - 191;
            const int a = p / 14;
            const int b = p - a * 14;
            const float ddx = locS[a * 3 + 0] - locD[b * 3 + 0] + EPS_C;
            const float ddy = locS[a * 3 + 1] - locD[b * 3 + 1] + EPS_C;
            const float ddz = locS[a * 3 + 2] - locD[b * 3 + 2] + EPS_C;
            v = sqrtf(ddx * ddx + ddy * ddy + ddz * ddz);
        }
        __builtin_nontemporal_store(v, o + idx);
    }
}

extern "C" void kernel_launch(void* const* d_in, const int* in_sizes, int n_in,
                              void* d_out, int out_size, void* d_ws, size_t ws_size,
                              hipStream_t stream) {
    const float* A  = (const float*)d_in[0];   // (N,14,3)
    const float* R  = (const float*)d_in[1];   // (N,3,3)
    const float* T  = (const float*)d_in[2];   // (N,3)
    const float* LG = (const float*)d_in[3];   // (N,21)
    const int*   EI = (const int*)d_in[4];     // (2,E)
    float* out = (float*)d_out;

    const int E = in_sizes[4] / 2;
    const int blocks = (E + WAVES_PER_BLOCK - 1) / WAVES_PER_BLOCK;
    edge_feat_kernel<<<blocks, 256, 0, stream>>>(A, R, T, LG, EI, out, E);
}

// Round 3
// 151.587 us; speedup vs baseline: 1.1769x; 1.1769x over previous
//
#include <hip/hip_runtime.h>
#include <math.h>

#define NUM_AA   21
#define OUT_DIM  387          // 1 + 21 + 21 + 64 + 42 + 42 + 196
#define SCALE    0.1f
#define EPS_C    1e-8f
#define WPB      4            // waves (edges) per block of 256 threads

typedef float v4f __attribute__((ext_vector_type(4)));

// One 64-lane wave per edge. Block stages its 4 complete output rows in LDS
// (contiguous 1548 floats = 6192 B, 16B-aligned), then flushes with aligned
// float4 nontemporal stores.
__global__ __launch_bounds__(256) void edge_feat_kernel(
    const float* __restrict__ A,    // (N,14,3) decoded_atom14
    const float* __restrict__ R,    // (N,3,3)  rot
    const float* __restrict__ T,    // (N,3)    trans
    const float* __restrict__ LG,   // (N,21)   decoded_seq_logits
    const int*   __restrict__ EI,   // (2,E)    edge_index [0]=dst, [1]=src
    float* __restrict__ out,        // (E,387)
    int E)
{
    __shared__ __align__(16) float rowsh[WPB * OUT_DIM];  // 4 output rows
    __shared__ float gsh[WPB][96];                        // a14s(42) a14d(42) rotS(9) tS(3)
    __shared__ int   seqsh[WPB][2];

    const int wv   = threadIdx.x >> 6;
    const int lane = threadIdx.x & 63;
    const int e    = blockIdx.x * WPB + wv;
    const bool valid = (e < E);
    const int ec = valid ? e : 0;

    float* row  = rowsh + wv * OUT_DIM;
    float* a14s = gsh[wv];
    float* a14d = gsh[wv] + 42;
    float* rotS = gsh[wv] + 84;
    float* tS   = gsh[wv] + 93;

    const int dst = EI[ec];
    const int src = EI[E + ec];

    // ---- gather phase (each wave stages its own edge's node data) ----
    if (lane < 42) {
        a14s[lane] = A[(size_t)src * 42 + lane] * SCALE;
        a14d[lane] = A[(size_t)dst * 42 + lane] * SCALE;
    } else if (lane < 51) {
        rotS[lane - 42] = R[(size_t)src * 9 + (lane - 42)];
    } else if (lane < 54) {
        tS[lane - 51] = T[(size_t)src * 3 + (lane - 51)] * SCALE;
    } else if (lane < 56) {
        // argmax over 21 logits (first-max wins, matches jnp.argmax)
        const int node = (lane == 54) ? src : dst;
        const float* lg = LG + (size_t)node * NUM_AA;
        float best = lg[0]; int bi = 0;
        #pragma unroll
        for (int j = 1; j < NUM_AA; ++j) {
            float v = lg[j];
            if (v > best) { best = v; bi = j; }
        }
        seqsh[wv][lane - 54] = bi;
    }
    __syncthreads();

    // ---- compute phase 1: rbf (all 64 lanes), ones+one-hots, locS/locD ----
    {
        // CA (atom 1) distance in the scaled global frame
        const float dx = a14d[3] - a14s[3];
        const float dy = a14d[4] - a14s[4];
        const float dz = a14d[5] - a14s[5];
        const float dca = sqrtf(dx * dx + dy * dy + dz * dz);
        const float mu = (float)lane * (20.0f / 63.0f);
        const float z  = (dca - mu) * 3.2f;   // 1/sigma = 64/20
        row[43 + lane] = __expf(-z * z);
    }
    if (lane < 43) {
        float v;
        if (lane == 0)       v = 1.0f;
        else if (lane < 22)  v = (lane - 1  == seqsh[wv][0]) ? 1.0f : 0.0f;
        else                 v = (lane - 22 == seqsh[wv][1]) ? 1.0f : 0.0f;
        row[lane] = v;
    }
    if (lane < 42) {
        const int a = lane / 3;
        const int i = lane - a * 3;
        // local[a,i] = sum_j rot[j,i] * (x[a,j] - t[j])
        const float r0 = rotS[i], r1 = rotS[3 + i], r2 = rotS[6 + i];
        const float t0 = tS[0], t1 = tS[1], t2 = tS[2];
        row[107 + lane] = r0 * (a14s[a * 3 + 0] - t0)
                        + r1 * (a14s[a * 3 + 1] - t1)
                        + r2 * (a14s[a * 3 + 2] - t2);
        row[149 + lane] = r0 * (a14d[a * 3 + 0] - t0)
                        + r1 * (a14d[a * 3 + 1] - t1)
                        + r2 * (a14d[a * 3 + 2] - t2);
    }
    __syncthreads();

    // ---- compute phase 2: 196 pair distances ----
    #pragma unroll
    for (int k = 0; k < 4; ++k) {
        const int p = lane + k * 64;
        if (p < 196) {
            const unsigned a = (unsigned)p / 14u;
            const unsigned b = (unsigned)p - a * 14u;
            const float ddx = row[107 + a * 3 + 0] - row[149 + b * 3 + 0] + EPS_C;
            const float ddy = row[107 + a * 3 + 1] - row[149 + b * 3 + 1] + EPS_C;
            const float ddz = row[107 + a * 3 + 2] - row[149 + b * 3 + 2] + EPS_C;
            row[191 + p] = sqrtf(ddx * ddx + ddy * ddy + ddz * ddz);
        }
    }
    __syncthreads();

    // ---- flush: block's 1548 contiguous floats as 387 aligned float4 ----
    const long long base = (long long)blockIdx.x * (WPB * OUT_DIM);
    const long long EF   = (long long)E * OUT_DIM;
    float* ob = out + base;
    const long long remain = EF - base;

    if (remain >= (long long)(WPB * OUT_DIM)) {
        const v4f* s4 = reinterpret_cast<const v4f*>(rowsh);
        v4f* o4 = reinterpret_cast<v4f*>(ob);
        #pragma unroll
        for (int k = 0; k < 2; ++k) {
            const int q = threadIdx.x + k * 256;
            if (q < (WPB * OUT_DIM) / 4) {   // 387 float4s
                __builtin_nontemporal_store(s4[q], o4 + q);
            }
        }
    } else if (remain > 0) {
        for (long long q = threadIdx.x; q < remain; q += 256) {
            __builtin_nontemporal_store(rowsh[q], ob + q);
        }
    }
}

extern "C" void kernel_launch(void* const* d_in, const int* in_sizes, int n_in,
                              void* d_out, int out_size, void* d_ws, size_t ws_size,
                              hipStream_t stream) {
    const float* A  = (const float*)d_in[0];   // (N,14,3)
    const float* R  = (const float*)d_in[1];   // (N,3,3)
    const float* T  = (const float*)d_in[2];   // (N,3)
    const float* LG = (const float*)d_in[3];   // (N,21)
    const int*   EI = (const int*)d_in[4];     // (2,E)
    float* out = (float*)d_out;

    const int E = in_sizes[4] / 2;
    const int blocks = (E + WPB - 1) / WPB;
    edge_feat_kernel<<<blocks, 256, 0, stream>>>(A, R, T, LG, EI, out, E);
}